// Round 3
// baseline (114.132 us; speedup 1.0000x reference)
//
#include <hip/hip_runtime.h>

// Problem constants (from reference)
#define NPTS   4096
#define NEVT   1000000
#define NQUAD  (NEVT / 4)                    // 250000, exact
#define TILE   64
#define NT     (NPTS / TILE)                 // 64 tiles per dim
#define PAIR_BLOCKS (NT * (NT + 1) / 2)      // 2080 upper-tri tile blocks
#define BLK    256
#define EVT_BLOCKS 512                        // 2 per CU (64 KB LDS each)

// Abramowitz-Stegun 7.1.26: |err| <= 1.5e-7, one exp + one rcp
__device__ __forceinline__ float fast_erff(float x) {
    float ax = __builtin_fabsf(x);
    float t  = __builtin_amdgcn_rcpf(__builtin_fmaf(0.3275911f, ax, 1.0f));
    float p  = __builtin_fmaf(t, 1.061405429f, -1.453152027f);
    p = __builtin_fmaf(t, p, 1.421413741f);
    p = __builtin_fmaf(t, p, -0.284496736f);
    p = __builtin_fmaf(t, p, 0.254829592f);
    p = p * t;
    float e = __builtin_amdgcn_exp2f(-ax * ax * 1.4426950408889634f);
    float r = __builtin_fmaf(-p, e, 1.0f);
    return __builtin_copysignf(r, x);
}

__device__ __forceinline__ void block_reduce_atomic(float contrib, float* red,
                                                    float* out, int tid) {
    #pragma unroll
    for (int off = 32; off > 0; off >>= 1)
        contrib += __shfl_down(contrib, off, 64);
    if ((tid & 63) == 0) red[tid >> 6] = contrib;
    __syncthreads();
    if (tid == 0) {
        float s = red[0] + red[1] + red[2] + red[3];
        atomicAdd(out, s);
    }
}

// ---- event term: sum_e (beta - ||dz0 + dv0*t||^2), LDS-staged point table
__global__ __launch_bounds__(BLK) void hawkes_events(
    const float* __restrict__ z0, const float* __restrict__ v0,
    const float* __restrict__ et, const int* __restrict__ uix,
    const int* __restrict__ vix, float* __restrict__ out)
{
    __shared__ float4 pts[NPTS];             // 64 KB -> 2 blocks/CU
    __shared__ float  red[BLK / 64];
    const int tid = threadIdx.x;
    const float2* z2 = (const float2*)z0;
    const float2* v2 = (const float2*)v0;

    #pragma unroll
    for (int k = 0; k < NPTS / BLK; ++k) {
        int p = tid + k * BLK;
        float2 zp = z2[p], vp = v2[p];
        pts[p] = make_float4(zp.x, zp.y, vp.x, vp.y);
    }
    __syncthreads();

    const int stride = EVT_BLOCKS * BLK;
    float acc = 0.0f;
    for (int q = (int)blockIdx.x * BLK + tid; q < NQUAD; q += stride) {
        int base = q * 4;
        float4 t4 = *(const float4*)(et + base);
        int4   u4 = *(const int4*)(uix + base);
        int4   v4 = *(const int4*)(vix + base);
        float tt[4] = {t4.x, t4.y, t4.z, t4.w};
        int   uu[4] = {u4.x, u4.y, u4.z, u4.w};
        int   vv[4] = {v4.x, v4.y, v4.z, v4.w};
        #pragma unroll
        for (int e = 0; e < 4; ++e) {
            float4 P = pts[uu[e]];
            float4 Q = pts[vv[e]];
            float dx = __builtin_fmaf(P.z - Q.z, tt[e], P.x - Q.x);
            float dy = __builtin_fmaf(P.w - Q.w, tt[e], P.y - Q.y);
            acc += 1.0f - (dx * dx + dy * dy);   // beta = 1
        }
    }
    block_reduce_atomic(acc, red, out, tid);
}

// ---- non-event (pair) term over upper-triangle 64x64 tiles
__global__ __launch_bounds__(BLK) void hawkes_pairs(
    const float* __restrict__ z0, const float* __restrict__ v0,
    const float* __restrict__ t0p, const float* __restrict__ tnp,
    float* __restrict__ out)
{
    __shared__ float4 tileJ[TILE];           // 1 KB -> full occupancy
    __shared__ float  red[BLK / 64];
    const int tid = threadIdx.x;
    const float2* z2 = (const float2*)z0;
    const float2* v2 = (const float2*)v0;
    const float t0 = *t0p;
    const float tn = *tnp;

    int L  = (int)blockIdx.x;
    // invert triangular row offset: O(bi) = bi*NT - bi*(bi-1)/2
    int bi = (int)((129.0f - sqrtf((float)(16641 - 8 * L))) * 0.5f);
    while (bi * NT - bi * (bi - 1) / 2 > L) --bi;
    while ((bi + 1) * NT - (bi + 1) * bi / 2 <= L) ++bi;
    int bj = bi + (L - (bi * NT - bi * (bi - 1) / 2));

    if (tid < TILE) {
        int j = bj * TILE + tid;
        float2 zj = z2[j], vj = v2[j];
        tileJ[tid] = make_float4(zj.x, zj.y, vj.x, vj.y);
    }
    __syncthreads();

    const int il = tid & 63;
    const int i  = bi * TILE + il;
    const float2 zi = z2[i];
    const float2 vi = v2[i];
    const int jw = tid >> 6;   // wave id 0..3: each wave owns 16 contiguous j's

    float acc = 0.0f;
    #pragma unroll
    for (int k = 0; k < 16; ++k) {
        int jl = jw * 16 + k;              // wave-uniform -> LDS broadcast read
        int j  = bj * TILE + jl;
        if (j > i) {                       // always true on off-diagonal tiles
            float4 tj = tileJ[jl];
            float a = zi.x - tj.x;
            float b = zi.y - tj.y;
            float m = vi.x - tj.z;
            float n = vi.y - tj.w;
            float mn2   = __builtin_fmaf(m, m, n * n);
            float cross = __builtin_fmaf(a, n, -b * m);
            float dot   = __builtin_fmaf(a, m, b * n);
            float invs  = __builtin_amdgcn_rsqf(mn2);     // 1/sqrt(mn2)
            float rmn2  = invs * invs;                    // 1/mn2, no extra rcp
            // alpha = beta = 1: exponent = 1 - cross^2 / mn2
            float ex    = __builtin_fmaf(-cross * cross, rmn2, 1.0f);
            float expo  = __builtin_amdgcn_exp2f(ex * 1.4426950408889634f);
            float arg0  = __builtin_fmaf(mn2, t0, dot) * invs;
            float arg1  = __builtin_fmaf(mn2, tn, dot) * invs;
            float df    = fast_erff(arg1) - fast_erff(arg0);
            acc = __builtin_fmaf(df * expo, invs, acc);
        }
    }
    // integral = sqrt(pi)/2 * expo * (erf1-erf0) * invs; output subtracts it
    block_reduce_atomic(-0.8862269254527580f * acc, red, out, tid);
}

extern "C" void kernel_launch(void* const* d_in, const int* in_sizes, int n_in,
                              void* d_out, int out_size, void* d_ws, size_t ws_size,
                              hipStream_t stream) {
    const float* z0  = (const float*)d_in[0];
    const float* v0  = (const float*)d_in[1];
    const float* et  = (const float*)d_in[2];
    const float* t0p = (const float*)d_in[3];
    const float* tnp = (const float*)d_in[4];
    const int*   uix = (const int*)d_in[5];
    const int*   vix = (const int*)d_in[6];
    float* out = (float*)d_out;

    hipMemsetAsync(out, 0, sizeof(float), stream);
    hipLaunchKernelGGL(hawkes_events, dim3(EVT_BLOCKS), dim3(BLK), 0, stream,
                       z0, v0, et, uix, vix, out);
    hipLaunchKernelGGL(hawkes_pairs, dim3(PAIR_BLOCKS), dim3(BLK), 0, stream,
                       z0, v0, t0p, tnp, out);
}

// Round 4
// 92.228 us; speedup vs baseline: 1.2375x; 1.2375x over previous
//
#include <hip/hip_runtime.h>

// Problem constants (from reference)
#define NPTS   4096
#define NEVT   1000000
#define NQUAD  (NEVT / 4)                    // 250000, exact (no tail)
#define TILE   64
#define NT     (NPTS / TILE)                 // 64 tiles per dim
#define PAIR_BLOCKS (NT * (NT + 1) / 2)      // 2080 upper-tri tile blocks
#define BLK    256
#define GRID   512                           // 2 blocks/CU (64 KB LDS each)

// Abramowitz-Stegun 7.1.26: |err| <= 1.5e-7, one exp + one rcp
__device__ __forceinline__ float fast_erff(float x) {
    float ax = __builtin_fabsf(x);
    float t  = __builtin_amdgcn_rcpf(__builtin_fmaf(0.3275911f, ax, 1.0f));
    float p  = __builtin_fmaf(t, 1.061405429f, -1.453152027f);
    p = __builtin_fmaf(t, p, 1.421413741f);
    p = __builtin_fmaf(t, p, -0.284496736f);
    p = __builtin_fmaf(t, p, 0.254829592f);
    p = p * t;
    float e = __builtin_amdgcn_exp2f(-ax * ax * 1.4426950408889634f);
    float r = __builtin_fmaf(-p, e, 1.0f);
    return __builtin_copysignf(r, x);
}

// One kernel, both phases per block: stage 64 KB point table once, then
// (1) grid-stride events via LDS gathers, (2) grid-stride pair tiles reading
// i- and j-fragments from the SAME staged table (no re-staging, no 2nd sync).
__global__ __launch_bounds__(BLK) void hawkes_fused(
    const float* __restrict__ z0, const float* __restrict__ v0,
    const float* __restrict__ et, const float* __restrict__ t0p,
    const float* __restrict__ tnp, const int* __restrict__ uix,
    const int* __restrict__ vix, float* __restrict__ out)
{
    __shared__ float4 pts[NPTS];             // 64 KB -> 2 blocks/CU
    __shared__ float  red[BLK / 64];
    const int tid = threadIdx.x;
    const float2* z2 = (const float2*)z0;
    const float2* v2 = (const float2*)v0;

    #pragma unroll
    for (int k = 0; k < NPTS / BLK; ++k) {
        int p = tid + k * BLK;
        float2 zp = z2[p], vp = v2[p];
        pts[p] = make_float4(zp.x, zp.y, vp.x, vp.y);
    }
    __syncthreads();

    // ---- phase 1: event term  sum_e (beta - ||dz0 + dv0*t||^2)
    float acc_ev = 0.0f;
    {
        const int stride = GRID * BLK;
        for (int q = (int)blockIdx.x * BLK + tid; q < NQUAD; q += stride) {
            int base = q * 4;
            float4 t4 = *(const float4*)(et + base);
            int4   u4 = *(const int4*)(uix + base);
            int4   v4 = *(const int4*)(vix + base);
            float tt[4] = {t4.x, t4.y, t4.z, t4.w};
            int   uu[4] = {u4.x, u4.y, u4.z, u4.w};
            int   vv[4] = {v4.x, v4.y, v4.z, v4.w};
            #pragma unroll
            for (int e = 0; e < 4; ++e) {
                float4 P = pts[uu[e]];
                float4 Q = pts[vv[e]];
                float dx = __builtin_fmaf(P.z - Q.z, tt[e], P.x - Q.x);
                float dy = __builtin_fmaf(P.w - Q.w, tt[e], P.y - Q.y);
                acc_ev += 1.0f - (dx * dx + dy * dy);   // beta = 1
            }
        }
    }

    // ---- phase 2: pair term over upper-triangle 64x64 tiles (grid-stride)
    const float t0 = *t0p;
    const float tn = *tnp;
    const int il = tid & 63;
    const int jw = tid >> 6;   // wave id 0..3: each wave owns 16 contiguous j's
    float acc_pr = 0.0f;
    for (int L = (int)blockIdx.x; L < PAIR_BLOCKS; L += GRID) {
        // invert triangular row offset: O(bi) = bi*NT - bi*(bi-1)/2
        int bi = (int)((129.0f - sqrtf((float)(16641 - 8 * L))) * 0.5f);
        while (bi * NT - bi * (bi - 1) / 2 > L) --bi;
        while ((bi + 1) * NT - (bi + 1) * bi / 2 <= L) ++bi;
        int bj = bi + (L - (bi * NT - bi * (bi - 1) / 2));

        const int i = bi * TILE + il;
        float4 Pi = pts[i];                 // lane-varying: b128, 2-way bank (free)
        #pragma unroll
        for (int k = 0; k < 16; ++k) {
            int jl = jw * 16 + k;           // wave-uniform -> LDS broadcast read
            int j  = bj * TILE + jl;
            if (j > i) {                    // always true on off-diagonal tiles
                float4 tj = pts[j];
                float a = Pi.x - tj.x;
                float b = Pi.y - tj.y;
                float m = Pi.z - tj.z;
                float n = Pi.w - tj.w;
                float mn2   = __builtin_fmaf(m, m, n * n);
                float cross = __builtin_fmaf(a, n, -b * m);
                float dot   = __builtin_fmaf(a, m, b * n);
                float invs  = __builtin_amdgcn_rsqf(mn2);     // 1/sqrt(mn2)
                float rmn2  = invs * invs;                    // 1/mn2 (no rcp)
                // alpha = beta = 1: exponent = 1 - cross^2/mn2
                float ex    = __builtin_fmaf(-cross * cross, rmn2, 1.0f);
                float expo  = __builtin_amdgcn_exp2f(ex * 1.4426950408889634f);
                float arg0  = __builtin_fmaf(mn2, t0, dot) * invs;
                float arg1  = __builtin_fmaf(mn2, tn, dot) * invs;
                float df    = fast_erff(arg1) - fast_erff(arg0);
                acc_pr = __builtin_fmaf(df * expo, invs, acc_pr);
            }
        }
    }

    // integral carries sqrt(pi)/2 factor; output = events - sum(integral)
    float contrib = __builtin_fmaf(-0.8862269254527580f, acc_pr, acc_ev);

    // ---- block reduction: wave shuffle -> LDS -> single atomic per block
    #pragma unroll
    for (int off = 32; off > 0; off >>= 1)
        contrib += __shfl_down(contrib, off, 64);
    if ((tid & 63) == 0) red[tid >> 6] = contrib;
    __syncthreads();
    if (tid == 0) {
        float s = red[0] + red[1] + red[2] + red[3];
        atomicAdd(out, s);
    }
}

extern "C" void kernel_launch(void* const* d_in, const int* in_sizes, int n_in,
                              void* d_out, int out_size, void* d_ws, size_t ws_size,
                              hipStream_t stream) {
    const float* z0  = (const float*)d_in[0];
    const float* v0  = (const float*)d_in[1];
    const float* et  = (const float*)d_in[2];
    const float* t0p = (const float*)d_in[3];
    const float* tnp = (const float*)d_in[4];
    const int*   uix = (const int*)d_in[5];
    const int*   vix = (const int*)d_in[6];
    float* out = (float*)d_out;

    hipMemsetAsync(out, 0, sizeof(float), stream);
    hipLaunchKernelGGL(hawkes_fused, dim3(GRID), dim3(BLK), 0, stream,
                       z0, v0, et, t0p, tnp, uix, vix, out);
}

// Round 5
// 90.478 us; speedup vs baseline: 1.2614x; 1.0193x over previous
//
#include <hip/hip_runtime.h>

// Problem constants (from reference)
#define NPTS   4096
#define NEVT   1000000
#define NQUAD  (NEVT / 4)                    // 250000, exact (no tail)
#define TILE   64
#define NT     (NPTS / TILE)                 // 64 tiles per dim
#define PAIR_BLOCKS (NT * (NT + 1) / 2)      // 2080 upper-tri tile blocks
#define BLK    512
#define GRID   512                           // 2 blocks/CU, 128 KB LDS, 32 waves/CU
#define NWAVES (GRID * (BLK / 64))           // 4096
#define NUNITS (PAIR_BLOCKS * 64)            // 133120 j-column wave-units
#define PERW   (NUNITS / NWAVES)             // 32
#define REMW   (NUNITS % NWAVES)             // 2048 (first 2048 waves do 33)

// Abramowitz-Stegun 7.1.26: |err| <= 1.5e-7, one exp + one rcp
__device__ __forceinline__ float fast_erff(float x) {
    float ax = __builtin_fabsf(x);
    float t  = __builtin_amdgcn_rcpf(__builtin_fmaf(0.3275911f, ax, 1.0f));
    float p  = __builtin_fmaf(t, 1.061405429f, -1.453152027f);
    p = __builtin_fmaf(t, p, 1.421413741f);
    p = __builtin_fmaf(t, p, -0.284496736f);
    p = __builtin_fmaf(t, p, 0.254829592f);
    p = p * t;
    float e = __builtin_amdgcn_exp2f(-ax * ax * 1.4426950408889634f);
    float r = __builtin_fmaf(-p, e, 1.0f);
    return __builtin_copysignf(r, x);
}

// One kernel, both phases per block: stage 64 KB point table once, then
// (1) events: one 4-event quad per thread via LDS gathers,
// (2) pairs: flat per-wave work units (one j-column of a 64x64 tile each)
//     for ~1.5% load imbalance; i from lane, j wave-uniform LDS broadcast.
__global__ __launch_bounds__(BLK, 4) void hawkes_fused(
    const float* __restrict__ z0, const float* __restrict__ v0,
    const float* __restrict__ et, const float* __restrict__ t0p,
    const float* __restrict__ tnp, const int* __restrict__ uix,
    const int* __restrict__ vix, float* __restrict__ out)
{
    __shared__ float4 pts[NPTS];             // 64 KB
    __shared__ float  red[BLK / 64];
    const int tid = threadIdx.x;
    const float2* z2 = (const float2*)z0;
    const float2* v2 = (const float2*)v0;

    #pragma unroll
    for (int k = 0; k < NPTS / BLK; ++k) {
        int p = tid + k * BLK;
        float2 zp = z2[p], vp = v2[p];
        pts[p] = make_float4(zp.x, zp.y, vp.x, vp.y);
    }
    __syncthreads();

    // ---- phase 1: event term  sum_e (beta - ||dz0 + dv0*t||^2)
    float acc_ev = 0.0f;
    {
        int q = (int)blockIdx.x * BLK + tid;     // 262144 threads >= 250000 quads
        if (q < NQUAD) {
            int base = q * 4;
            float4 t4 = *(const float4*)(et + base);
            int4   u4 = *(const int4*)(uix + base);
            int4   v4 = *(const int4*)(vix + base);
            float tt[4] = {t4.x, t4.y, t4.z, t4.w};
            int   uu[4] = {u4.x, u4.y, u4.z, u4.w};
            int   vv[4] = {v4.x, v4.y, v4.z, v4.w};
            #pragma unroll
            for (int e = 0; e < 4; ++e) {
                float4 P = pts[uu[e]];
                float4 Q = pts[vv[e]];
                float dx = __builtin_fmaf(P.z - Q.z, tt[e], P.x - Q.x);
                float dy = __builtin_fmaf(P.w - Q.w, tt[e], P.y - Q.y);
                acc_ev += 1.0f - (dx * dx + dy * dy);   // beta = 1
            }
        }
    }

    // ---- phase 2: pair term, flat wave-unit distribution
    const float t0 = *t0p;
    const float tn = *tnp;
    const int il  = tid & 63;
    const int wid = (int)blockIdx.x * (BLK / 64) + (tid >> 6);
    int n = PERW + (wid < REMW ? 1 : 0);
    int u = wid * PERW + (wid < REMW ? wid : REMW);
    int Lc = -1, ibase = 0, jbase = 0;
    float4 Pi = make_float4(0.f, 0.f, 0.f, 0.f);
    float acc_pr = 0.0f;
    for (int s = 0; s < n; ++s, ++u) {
        int L  = u >> 6;                   // tile index (wave-uniform)
        int jl = u & 63;                   // j-column within tile
        if (L != Lc) {                     // runs <= 2x per wave (33-unit span)
            int bi = (int)((129.0f - sqrtf((float)(16641 - 8 * L))) * 0.5f);
            while (bi * NT - bi * (bi - 1) / 2 > L) --bi;
            while ((bi + 1) * NT - (bi + 1) * bi / 2 <= L) ++bi;
            int bj = bi + (L - (bi * NT - bi * (bi - 1) / 2));
            ibase = bi * TILE; jbase = bj * TILE;
            Pi = pts[ibase + il];          // lane-varying b128, 2-way bank (free)
            Lc = L;
        }
        int i = ibase + il;
        int j = jbase + jl;
        if (j > i) {                       // masks lanes only on diagonal tiles
            float4 tj = pts[j];            // wave-uniform -> broadcast
            float a = Pi.x - tj.x;
            float b = Pi.y - tj.y;
            float m = Pi.z - tj.z;
            float nn = Pi.w - tj.w;
            float mn2   = __builtin_fmaf(m, m, nn * nn);
            float cross = __builtin_fmaf(a, nn, -b * m);
            float dot   = __builtin_fmaf(a, m, b * nn);
            float invs  = __builtin_amdgcn_rsqf(mn2);     // 1/sqrt(mn2)
            float rmn2  = invs * invs;                    // 1/mn2 (no rcp)
            // alpha = beta = 1: exponent = 1 - cross^2/mn2
            float ex    = __builtin_fmaf(-cross * cross, rmn2, 1.0f);
            float expo  = __builtin_amdgcn_exp2f(ex * 1.4426950408889634f);
            float arg0  = __builtin_fmaf(mn2, t0, dot) * invs;
            float arg1  = __builtin_fmaf(mn2, tn, dot) * invs;
            float df    = fast_erff(arg1) - fast_erff(arg0);
            acc_pr = __builtin_fmaf(df * expo, invs, acc_pr);
        }
    }

    // integral carries sqrt(pi)/2 factor; output = events - sum(integral)
    float contrib = __builtin_fmaf(-0.8862269254527580f, acc_pr, acc_ev);

    // ---- block reduction: wave shuffle -> LDS -> single atomic per block
    #pragma unroll
    for (int off = 32; off > 0; off >>= 1)
        contrib += __shfl_down(contrib, off, 64);
    if ((tid & 63) == 0) red[tid >> 6] = contrib;
    __syncthreads();
    if (tid == 0) {
        float s = 0.0f;
        #pragma unroll
        for (int w = 0; w < BLK / 64; ++w) s += red[w];
        atomicAdd(out, s);
    }
}

extern "C" void kernel_launch(void* const* d_in, const int* in_sizes, int n_in,
                              void* d_out, int out_size, void* d_ws, size_t ws_size,
                              hipStream_t stream) {
    const float* z0  = (const float*)d_in[0];
    const float* v0  = (const float*)d_in[1];
    const float* et  = (const float*)d_in[2];
    const float* t0p = (const float*)d_in[3];
    const float* tnp = (const float*)d_in[4];
    const int*   uix = (const int*)d_in[5];
    const int*   vix = (const int*)d_in[6];
    float* out = (float*)d_out;

    hipMemsetAsync(out, 0, sizeof(float), stream);
    hipLaunchKernelGGL(hawkes_fused, dim3(GRID), dim3(BLK), 0, stream,
                       z0, v0, et, t0p, tnp, uix, vix, out);
}